// Round 10
// baseline (1543.051 us; speedup 1.0000x reference)
//
#include <hip/hip_runtime.h>

// Problem constants
#define D_DIM 1024
#define L_DIM 4096
#define B_DIM 4
#define M_DIM (B_DIM * L_DIM)   // 16384 rows
#define N1    3072              // concat of K1|Q1|K2 outputs
#define KDIM  1024
#define NT32  32                // K tiles of 32
#define KAPPA 6.25e-4f          // 0.02 / sqrt(1024)

using f32x4  = __attribute__((ext_vector_type(4))) float;
using bf16x8 = __attribute__((ext_vector_type(8))) short;

__device__ __forceinline__ unsigned short f2bf(float f) {
    unsigned u = __float_as_uint(f);
    u += 0x7fffu + ((u >> 16) & 1u);   // RNE
    return (unsigned short)(u >> 16);
}
__device__ __forceinline__ float bflo(unsigned u) { return __uint_as_float(u << 16); }
__device__ __forceinline__ float bfhi(unsigned u) { return __uint_as_float(u & 0xffff0000u); }
__device__ __forceinline__ unsigned pack2(float a, float b) {
    return (unsigned)f2bf(a) | ((unsigned)f2bf(b) << 16);
}
__device__ __forceinline__ float sigmoidf_(float x) {
    return 1.0f / (1.0f + __expf(-x));
}

// merged fp32->bf16 conversion: x (16384 blocks) then 4 weight mats (4096 blocks)
__global__ void cvt_all_kernel(const float* __restrict__ x,
                               const float* __restrict__ w0, const float* __restrict__ w1,
                               const float* __restrict__ w2, const float* __restrict__ w3,
                               unsigned short* __restrict__ xbf, unsigned short* __restrict__ wout) {
    int bid = blockIdx.x;
    const float* src;
    unsigned short* dst;
    int i;
    if (bid < 16384) {
        src = x; dst = xbf;
        i = (bid * 256 + threadIdx.x) * 4;
    } else {
        int wb = bid - 16384;
        int seg = wb >> 10;
        src = (seg == 0) ? w0 : (seg == 1) ? w1 : (seg == 2) ? w2 : w3;
        dst = wout + seg * 1048576;
        i = ((wb & 1023) * 256 + threadIdx.x) * 4;
    }
    float4 v = *reinterpret_cast<const float4*>(src + i);
    uint2 p;
    p.x = pack2(v.x, v.y);
    p.y = pack2(v.z, v.w);
    *reinterpret_cast<uint2*>(dst + i) = p;
}

__device__ __forceinline__ void gld_lds16(const void* g, void* s) {
    __builtin_amdgcn_global_load_lds((const __attribute__((address_space(1))) void*)g,
                                     (__attribute__((address_space(3))) void*)s, 16, 0, 0);
}

#define BAR()  do { asm volatile("" ::: "memory"); __builtin_amdgcn_s_barrier(); asm volatile("" ::: "memory"); } while (0)
#define MFMA16(a_, b_, c_) __builtin_amdgcn_mfma_f32_16x16x32_bf16(a_, b_, c_, 0, 0, 0)

// ============================================================================
// 256x256 tile, BK=32, 8 waves (2M x 4N), 512 threads, 64 KiB LDS dbuf
// -> 2 blocks/CU (the round-10 change; schedule math identical to round 8:
//    same barriers/K, same MFMA/phase, same staging-call count, same 64B-row
//    swizzled addressing).
// Per K-tile (2 phases):
//   P1: { a0..7 + b0,b1 ds_reads(cur); stage B(kt+1)->nc x2; BAR; 16 MFMA; BAR }
//   P2: { b2,b3 ds_reads(cur);        stage A(kt+2)->cur x2; BAR; 16 MFMA;
//         vmcnt(2) [drains A/B(kt+1), leaves A(kt+2)]; BAR }
// Hazards: nc.B last consumed >=1 barrier before P1's stage; cur.A reads
// landed by P1-MFMA lgkm => P1-end BAR precedes P2's A-stage. Prologue stages
// A(0),B(0),A(1) then vmcnt(2).
// ============================================================================
__global__ __launch_bounds__(512, 4) void gemm256(
        const unsigned short* __restrict__ A, const unsigned short* __restrict__ Bm,
        unsigned short* __restrict__ Cb, float* __restrict__ Cf,
        const float* __restrict__ bb0, const float* __restrict__ bb1, const float* __restrict__ bb2,
        int nwgDiv8, int mode) {
    extern __shared__ __align__(16) short lds[];
    const int tid  = threadIdx.x;
    const int wid  = tid >> 6, lane = tid & 63;
    const int wr   = wid >> 2, wc = wid & 3;
    const int lr   = lane & 15, kg = lane >> 4;

    int lin = blockIdx.y * 64 + blockIdx.x;
    int swz = (lin & 7) * nwgDiv8 + (lin >> 3);
    int bm = swz & 63;
    int bn = swz >> 6;
    const size_t rowA0 = (size_t)bm * 256;
    const size_t rowB0 = (size_t)bn * 256;

    const int rh = tid >> 2;
    const int sl = (tid & 3) ^ ((rh >> 1) & 3);
    const int wbase = (tid >> 6) * 512;
    const size_t aoffG = (size_t)rh * KDIM + sl * 8;

    // one call covers 128 rows x 32 cols (4096 shorts); 2 calls per matrix tile
#define STG(Mp_, row0_, kt_, c_, mat_, cur_) \
    gld_lds16((Mp_) + ((row0_) + (size_t)(c_) * 128) * KDIM + (size_t)(kt_) * 32 + aoffG, \
              (void*)(lds + (cur_) * 16384 + (mat_) * 8192 + (c_) * 4096 + wbase))

    const int slotR = kg ^ ((lr >> 1) & 3);
    const int aRd = (wr * 128 + lr) * 32 + slotR * 8;   // + fm*512
    const int bRd = (wc * 64  + lr) * 32 + slotR * 8;   // + fn*512

    f32x4 acc[8][4];
#pragma unroll
    for (int i = 0; i < 8; ++i)
#pragma unroll
        for (int j = 0; j < 4; ++j) acc[i][j] = (f32x4){0.f, 0.f, 0.f, 0.f};

    // prologue: A(0), B(0) -> buf0; A(1) -> buf1; drain to A(1)-only in flight
    STG(A,  rowA0, 0, 0, 0, 0); STG(A,  rowA0, 0, 1, 0, 0);
    STG(Bm, rowB0, 0, 0, 1, 0); STG(Bm, rowB0, 0, 1, 1, 0);
    STG(A,  rowA0, 1, 0, 0, 1); STG(A,  rowA0, 1, 1, 0, 1);
    asm volatile("s_waitcnt vmcnt(2)" ::: "memory");
    BAR();

    for (int kt = 0; kt < NT32; ++kt) {
        const int cur = kt & 1;
        const int nc  = cur ^ 1;
        const short* Ab = lds + cur * 16384;
        const short* Bb = Ab + 8192;
        bf16x8 a[8], b0, b1, b2, b3;

        // ---- P1
        #pragma unroll
        for (int fm = 0; fm < 8; ++fm) a[fm] = *reinterpret_cast<const bf16x8*>(Ab + aRd + fm * 512);
        b0 = *reinterpret_cast<const bf16x8*>(Bb + bRd);
        b1 = *reinterpret_cast<const bf16x8*>(Bb + bRd + 512);
        if (kt + 1 < NT32) {
            STG(Bm, rowB0, kt + 1, 0, 1, nc); STG(Bm, rowB0, kt + 1, 1, 1, nc);
        }
        BAR();
        __builtin_amdgcn_s_setprio(1);
        #pragma unroll
        for (int fm = 0; fm < 8; ++fm) {
            acc[fm][0] = MFMA16(b0, a[fm], acc[fm][0]);
            acc[fm][1] = MFMA16(b1, a[fm], acc[fm][1]);
        }
        __builtin_amdgcn_s_setprio(0);
        BAR();

        // ---- P2
        b2 = *reinterpret_cast<const bf16x8*>(Bb + bRd + 1024);
        b3 = *reinterpret_cast<const bf16x8*>(Bb + bRd + 1536);
        if (kt + 2 < NT32) {
            STG(A, rowA0, kt + 2, 0, 0, cur); STG(A, rowA0, kt + 2, 1, 0, cur);
        }
        BAR();
        __builtin_amdgcn_s_setprio(1);
        #pragma unroll
        for (int fm = 0; fm < 8; ++fm) {
            acc[fm][2] = MFMA16(b2, a[fm], acc[fm][2]);
            acc[fm][3] = MFMA16(b3, a[fm], acc[fm][3]);
        }
        __builtin_amdgcn_s_setprio(0);
        if (kt < NT32 - 2) { asm volatile("s_waitcnt vmcnt(2)" ::: "memory"); }
        else               { asm volatile("s_waitcnt vmcnt(0)" ::: "memory"); }
        BAR();
    }

    const int rowBase = bm * 256 + wr * 128;
    const int colBase = bn * 256 + wc * 64;
    if (mode == 0) {
        const int seg = (colBase >> 10);
        const float* bs = (seg == 0) ? bb0 : ((seg == 1) ? bb1 : bb2);
#pragma unroll
        for (int fm = 0; fm < 8; ++fm) {
            int row = rowBase + fm * 16 + lr;
            unsigned short* cp = Cb + (size_t)row * 3072;
#pragma unroll
            for (int fn = 0; fn < 4; ++fn) {
                int col0 = colBase + fn * 16 + kg * 4;
                float4 b4 = *reinterpret_cast<const float4*>(bs + (col0 & 1023));
                float v0 = acc[fm][fn][0] + b4.x;
                float v1 = acc[fm][fn][1] + b4.y;
                float v2 = acc[fm][fn][2] + b4.z;
                float v3 = acc[fm][fn][3] + b4.w;
                float r0, r1, r2, r3;
                if (seg == 0)      { r0 = __expf(v0); r1 = __expf(v1); r2 = __expf(v2); r3 = __expf(v3); }
                else if (seg == 1) { r0 = sigmoidf_(v0); r1 = sigmoidf_(v1); r2 = sigmoidf_(v2); r3 = sigmoidf_(v3); }
                else               { r0 = sigmoidf_(v0 * KAPPA); r1 = sigmoidf_(v1 * KAPPA);
                                     r2 = sigmoidf_(v2 * KAPPA); r3 = sigmoidf_(v3 * KAPPA); }
                uint2 p;
                p.x = pack2(r0, r1);
                p.y = pack2(r2, r3);
                *reinterpret_cast<uint2*>(cp + col0) = p;
            }
        }
    } else {
#pragma unroll
        for (int fm = 0; fm < 8; ++fm) {
            int row = rowBase + fm * 16 + lr;
            float* cp = Cf + (size_t)row * 1024;
#pragma unroll
            for (int fn = 0; fn < 4; ++fn) {
                int col0 = colBase + fn * 16 + kg * 4;
                float4 b4 = *reinterpret_cast<const float4*>(bb0 + col0);
                float4 v;
                v.x = acc[fm][fn][0] + b4.x;
                v.y = acc[fm][fn][1] + b4.y;
                v.z = acc[fm][fn][2] + b4.z;
                v.w = acc[fm][fn][3] + b4.w;
                *reinterpret_cast<float4*>(cp + col0) = v;
            }
        }
    }
#undef STG
}

// ============================================================================
// Split scan chain, 2 channels/thread (uint = 2 bf16 per load).
// Block: blockIdx.x = (b*64 + c)*2 + dq; 256 threads; d0 = dq*512 + thr*2.
// Partials layout: [b*64+c][512 dpairs] float2, dpair = dq*256 + thr.
// ============================================================================

// pass1: per-(b,chunk) partial sums of K and K*V
__global__ __launch_bounds__(256) void pass1v(
        const unsigned short* __restrict__ KQ, const unsigned short* __restrict__ xbf,
        float2* __restrict__ pK, float2* __restrict__ pKV) {
    const int thr = threadIdx.x;
    const int dq = blockIdx.x & 1;
    const int bc = blockIdx.x >> 1;
    const int b = bc >> 6, c = bc & 63;
    const int d0 = dq * 512 + thr * 2;
    const size_t row0 = (size_t)b * L_DIM + (size_t)c * 64;
    const unsigned short* kp = KQ  + row0 * 3072 + d0;
    const unsigned short* vp = xbf + row0 * 1024 + d0;
    float sK0 = 0.f, sK1 = 0.f, sKV0 = 0.f, sKV1 = 0.f;
#pragma unroll 8
    for (int t = 0; t < 64; ++t) {
        unsigned ku = *reinterpret_cast<const unsigned*>(kp + (size_t)t * 3072);
        unsigned vu = *reinterpret_cast<const unsigned*>(vp + (size_t)t * 1024);
        sK0 += bflo(ku); sK1 += bfhi(ku);
        sKV0 += bflo(ku) * bflo(vu); sKV1 += bfhi(ku) * bfhi(vu);
    }
    const size_t slot = (size_t)bc * 512 + dq * 256 + thr;
    pK[slot]  = make_float2(sK0, sK1);
    pKV[slot] = make_float2(sKV0, sKV1);
}

// pass3: lookback over pK/pKV, then z[t] = oar[t] + P[t]*KAPPA*q[t-1]; chunk sum of m
__global__ __launch_bounds__(256) void pass3v(
        const unsigned short* __restrict__ KQ, const unsigned short* __restrict__ xbf,
        const float2* __restrict__ pK, const float2* __restrict__ pKV,
        unsigned short* __restrict__ z, float2* __restrict__ pM) {
    const int thr = threadIdx.x;
    const int dq = blockIdx.x & 1;
    const int bc = blockIdx.x >> 1;
    const int b = bc >> 6, c = bc & 63;
    const int d0 = dq * 512 + thr * 2;
    const size_t row0 = (size_t)b * L_DIM + (size_t)c * 64;
    const unsigned short* kqp = KQ  + row0 * 3072 + d0;   // k:+0  q:+1024  k2:+2048
    const unsigned short* vp  = xbf + row0 * 1024 + d0;
    unsigned short* zp = z + row0 * 1024 + d0;

    // lookback: exclusive prefix over chunks (ascending -> deterministic)
    float cK0 = 0.f, cK1 = 0.f, cKV0 = 0.f, cKV1 = 0.f;
    const size_t base = (size_t)(b << 6) * 512 + dq * 256 + thr;
#pragma unroll 4
    for (int cp = 0; cp < c; ++cp) {
        float2 a = pK [base + (size_t)cp * 512];
        float2 q2 = pKV[base + (size_t)cp * 512];
        cK0 += a.x; cK1 += a.y; cKV0 += q2.x; cKV1 += q2.y;
    }

    float oar_prev0 = 0.f, oar_prev1 = 0.f, k2_prev0 = 0.f, k2_prev1 = 0.f;
    float q_prev0 = 0.f, q_prev1 = 0.f;
    if (c != 0) {
        unsigned qm  = *reinterpret_cast<const unsigned*>(kqp - 3072 + 1024);
        unsigned k2m = *reinterpret_cast<const unsigned*>(kqp - 3072 + 2048);
        oar_prev0 = bflo(qm) * (cKV0 / (cK0 + 1e-6f));
        oar_prev1 = bfhi(qm) * (cKV1 / (cK1 + 1e-6f));
        k2_prev0 = bflo(k2m); k2_prev1 = bfhi(k2m);
        q_prev0 = bflo(qm);   q_prev1 = bfhi(qm);
    }
    float sM0 = 0.f, sM1 = 0.f;
#pragma unroll 4
    for (int t = 0; t < 64; ++t) {
        unsigned ku  = *reinterpret_cast<const unsigned*>(kqp + (size_t)t * 3072);
        unsigned qu  = *reinterpret_cast<const unsigned*>(kqp + (size_t)t * 3072 + 1024);
        unsigned k2u = *reinterpret_cast<const unsigned*>(kqp + (size_t)t * 3072 + 2048);
        unsigned vu  = *reinterpret_cast<const unsigned*>(vp  + (size_t)t * 1024);
        float v0 = bflo(vu), v1 = bfhi(vu);
        cK0 += bflo(ku); cKV0 += bflo(ku) * v0;
        cK1 += bfhi(ku); cKV1 += bfhi(ku) * v1;
        float oar0 = bflo(qu) * (cKV0 / (cK0 + 1e-6f));
        float oar1 = bfhi(qu) * (cKV1 / (cK1 + 1e-6f));
        float m0 = k2_prev0 * (v0 - oar_prev0);   // t==0 && c==0: all zero -> m=0
        float m1 = k2_prev1 * (v1 - oar_prev1);
        sM0 += m0; sM1 += m1;
        float z0 = oar0 + sM0 * KAPPA * q_prev0;
        float z1 = oar1 + sM1 * KAPPA * q_prev1;
        *reinterpret_cast<unsigned*>(zp + (size_t)t * 1024) = pack2(z0, z1);
        oar_prev0 = oar0; oar_prev1 = oar1;
        k2_prev0 = bflo(k2u); k2_prev1 = bfhi(k2u);
        q_prev0 = bflo(qu);   q_prev1 = bfhi(qu);
    }
    pM[(size_t)bc * 512 + dq * 256 + thr] = make_float2(sM0, sM1);
}

// pass5: yin[t] = z[t] + offM*KAPPA*q[t-1], in place on z. chunk 0: identity.
__global__ __launch_bounds__(256) void pass5v(
        const unsigned short* __restrict__ KQ, unsigned short* __restrict__ zy,
        const float2* __restrict__ pM) {
    const int thr = threadIdx.x;
    const int dq = blockIdx.x & 1;
    const int bc = blockIdx.x >> 1;
    const int b = bc >> 6, c = bc & 63;
    if (c == 0) return;                    // offM == 0 -> yin == z
    const int d0 = dq * 512 + thr * 2;
    const size_t row0 = (size_t)b * L_DIM + (size_t)c * 64;

    float offM0 = 0.f, offM1 = 0.f;
    const size_t base = (size_t)(b << 6) * 512 + dq * 256 + thr;
#pragma unroll 4
    for (int cp = 0; cp < c; ++cp) {
        float2 a = pM[base + (size_t)cp * 512];
        offM0 += a.x; offM1 += a.y;
    }
    const float s0 = offM0 * KAPPA, s1 = offM1 * KAPPA;
    const unsigned short* qp = KQ + (row0 - 1) * 3072 + 1024 + d0;   // q[t-1]
    unsigned short* zp = zy + row0 * 1024 + d0;
#pragma unroll 8
    for (int t = 0; t < 64; ++t) {
        unsigned qu = *reinterpret_cast<const unsigned*>(qp + (size_t)t * 3072);
        unsigned zu = *reinterpret_cast<const unsigned*>(zp + (size_t)t * 1024);
        float y0 = bflo(zu) + s0 * bflo(qu);
        float y1 = bfhi(zu) + s1 * bfhi(qu);
        *reinterpret_cast<unsigned*>(zp + (size_t)t * 1024) = pack2(y0, y1);
    }
}

extern "C" void kernel_launch(void* const* d_in, const int* in_sizes, int n_in,
                              void* d_out, int out_size, void* d_ws, size_t ws_size,
                              hipStream_t stream) {
    (void)in_sizes; (void)n_in; (void)out_size; (void)ws_size;
    const float* x   = (const float*)d_in[0];
    const float* Wq1 = (const float*)d_in[1];
    const float* bq1 = (const float*)d_in[2];
    const float* Wk1 = (const float*)d_in[3];
    const float* bk1 = (const float*)d_in[4];
    const float* Wk2 = (const float*)d_in[5];
    const float* bk2 = (const float*)d_in[6];
    const float* Wpj = (const float*)d_in[7];
    const float* bpj = (const float*)d_in[8];
    float* out = (float*)d_out;

    char* ws = (char*)d_ws;
    unsigned short* xbf   = (unsigned short*)(ws);                  // 33,554,432 B
    unsigned short* Wcat  = (unsigned short*)(ws + 33554432);       //  6,291,456 B (Wk1|Wq1|Wk2)
    unsigned short* Wpjbf = (unsigned short*)(ws + 39845888);       //  2,097,152 B (contiguous after Wcat)
    unsigned short* KQ    = (unsigned short*)(ws + 41943040);       // 100,663,296 B
    unsigned short* zy    = (unsigned short*)(ws + 142606336);      // 33,554,432 B (z, then yin in place)
    float2* pK  = (float2*)(ws + 176160768);                        // 1,048,576 B
    float2* pKV = (float2*)(ws + 177209344);                        // 1,048,576 B
    float2* pM  = (float2*)(ws + 178257920);                        // 1,048,576 B
    // total ~171 MiB

    (void)hipFuncSetAttribute((const void*)gemm256,
                              hipFuncAttributeMaxDynamicSharedMemorySize, 65536);

    // merged conversions: x + 4 weight matrices (Wcat|Wpjbf contiguous)
    cvt_all_kernel<<<20480, 256, 0, stream>>>(x, Wk1, Wq1, Wk2, Wpj, xbf, Wcat);

    // GEMM1: 16384 x 3072 x 1024, bf16 out with activations
    gemm256<<<dim3(64, 12), 512, 65536, stream>>>(xbf, Wcat, KQ, nullptr,
                                                  bk1, bq1, bk2, 96, 0);

    // scan chain: pass1 -> pass3 (z) -> pass5 (yin in place)
    pass1v<<<512, 256, 0, stream>>>(KQ, xbf, pK, pKV);
    pass3v<<<512, 256, 0, stream>>>(KQ, xbf, pK, pKV, zy, pM);
    pass5v<<<512, 256, 0, stream>>>(KQ, zy, pM);

    // GEMM2: 16384 x 1024 x 1024, fp32 out with bias
    gemm256<<<dim3(64, 4), 512, 65536, stream>>>(zy, Wpjbf, nullptr, out,
                                                 bpj, nullptr, nullptr, 32, 1);
}

// Round 11
// 268.843 us; speedup vs baseline: 5.7396x; 5.7396x over previous
//
#include <hip/hip_runtime.h>

// Problem constants
#define D_DIM 1024
#define L_DIM 4096
#define B_DIM 4
#define M_DIM (B_DIM * L_DIM)   // 16384 rows
#define N1    3072              // concat of K1|Q1|K2 outputs
#define KDIM  1024
#define NT32  32                // K tiles of 32
#define KAPPA 6.25e-4f          // 0.02 / sqrt(1024)

using f32x4  = __attribute__((ext_vector_type(4))) float;
using bf16x8 = __attribute__((ext_vector_type(8))) short;

__device__ __forceinline__ unsigned short f2bf(float f) {
    unsigned u = __float_as_uint(f);
    u += 0x7fffu + ((u >> 16) & 1u);   // RNE
    return (unsigned short)(u >> 16);
}
__device__ __forceinline__ float bflo(unsigned u) { return __uint_as_float(u << 16); }
__device__ __forceinline__ float bfhi(unsigned u) { return __uint_as_float(u & 0xffff0000u); }
__device__ __forceinline__ unsigned pack2(float a, float b) {
    return (unsigned)f2bf(a) | ((unsigned)f2bf(b) << 16);
}
__device__ __forceinline__ float sigmoidf_(float x) {
    return 1.0f / (1.0f + __expf(-x));
}

// merged fp32->bf16 conversion: x (16384 blocks) then 4 weight mats (4096 blocks)
__global__ void cvt_all_kernel(const float* __restrict__ x,
                               const float* __restrict__ w0, const float* __restrict__ w1,
                               const float* __restrict__ w2, const float* __restrict__ w3,
                               unsigned short* __restrict__ xbf, unsigned short* __restrict__ wout) {
    int bid = blockIdx.x;
    const float* src;
    unsigned short* dst;
    int i;
    if (bid < 16384) {
        src = x; dst = xbf;
        i = (bid * 256 + threadIdx.x) * 4;
    } else {
        int wb = bid - 16384;
        int seg = wb >> 10;
        src = (seg == 0) ? w0 : (seg == 1) ? w1 : (seg == 2) ? w2 : w3;
        dst = wout + seg * 1048576;
        i = ((wb & 1023) * 256 + threadIdx.x) * 4;
    }
    float4 v = *reinterpret_cast<const float4*>(src + i);
    uint2 p;
    p.x = pack2(v.x, v.y);
    p.y = pack2(v.z, v.w);
    *reinterpret_cast<uint2*>(dst + i) = p;
}

__device__ __forceinline__ void gld_lds16(const void* g, void* s) {
    __builtin_amdgcn_global_load_lds((const __attribute__((address_space(1))) void*)g,
                                     (__attribute__((address_space(3))) void*)s, 16, 0, 0);
}

#define BAR()  do { asm volatile("" ::: "memory"); __builtin_amdgcn_s_barrier(); asm volatile("" ::: "memory"); } while (0)
#define MFMA16(a_, b_, c_) __builtin_amdgcn_mfma_f32_16x16x32_bf16(a_, b_, c_, 0, 0, 0)

// ============================================================================
// 256x256 tile, BK=32, 8 waves (2M x 4N), 512 threads, 64 KiB LDS dbuf.
// __launch_bounds__(512,2): round-10's (512,4) forced the allocator to spill
// the whole acc[8][4] (VGPR 64, 1.8 GB FETCH). (512,2) compiled round 8 to
// exactly 128 VGPR; at <=128 VGPR + 64 KiB LDS the HW gives 2 blocks/CU.
// Per K-tile (2 phases):
//   P1: { a0..7 + b0,b1 ds_reads(cur); stage B(kt+1)->nc x2; BAR; 16 MFMA; BAR }
//   P2: { b2,b3 ds_reads(cur);        stage A(kt+2)->cur x2; BAR; 16 MFMA;
//         vmcnt(2) [drains A/B(kt+1), leaves A(kt+2)]; BAR }
// Hazards: nc.B last consumed >=1 barrier before P1's stage; cur.A reads
// landed by P1-MFMA lgkm => P1-end BAR precedes P2's A-stage. Prologue stages
// A(0),B(0),A(1) then vmcnt(2).
// ============================================================================
__global__ __launch_bounds__(512, 2) void gemm256(
        const unsigned short* __restrict__ A, const unsigned short* __restrict__ Bm,
        unsigned short* __restrict__ Cb, float* __restrict__ Cf,
        const float* __restrict__ bb0, const float* __restrict__ bb1, const float* __restrict__ bb2,
        int nwgDiv8, int mode) {
    extern __shared__ __align__(16) short lds[];
    const int tid  = threadIdx.x;
    const int wid  = tid >> 6, lane = tid & 63;
    const int wr   = wid >> 2, wc = wid & 3;
    const int lr   = lane & 15, kg = lane >> 4;

    int lin = blockIdx.y * 64 + blockIdx.x;
    int swz = (lin & 7) * nwgDiv8 + (lin >> 3);
    int bm = swz & 63;
    int bn = swz >> 6;
    const size_t rowA0 = (size_t)bm * 256;
    const size_t rowB0 = (size_t)bn * 256;

    const int rh = tid >> 2;
    const int sl = (tid & 3) ^ ((rh >> 1) & 3);
    const int wbase = (tid >> 6) * 512;
    const size_t aoffG = (size_t)rh * KDIM + sl * 8;

    // one call covers 128 rows x 32 cols (4096 shorts); 2 calls per matrix tile
#define STG(Mp_, row0_, kt_, c_, mat_, cur_) \
    gld_lds16((Mp_) + ((row0_) + (size_t)(c_) * 128) * KDIM + (size_t)(kt_) * 32 + aoffG, \
              (void*)(lds + (cur_) * 16384 + (mat_) * 8192 + (c_) * 4096 + wbase))

    const int slotR = kg ^ ((lr >> 1) & 3);
    const int aRd = (wr * 128 + lr) * 32 + slotR * 8;   // + fm*512
    const int bRd = (wc * 64  + lr) * 32 + slotR * 8;   // + fn*512

    f32x4 acc[8][4];
#pragma unroll
    for (int i = 0; i < 8; ++i)
#pragma unroll
        for (int j = 0; j < 4; ++j) acc[i][j] = (f32x4){0.f, 0.f, 0.f, 0.f};

    // prologue: A(0), B(0) -> buf0; A(1) -> buf1; drain to A(1)-only in flight
    STG(A,  rowA0, 0, 0, 0, 0); STG(A,  rowA0, 0, 1, 0, 0);
    STG(Bm, rowB0, 0, 0, 1, 0); STG(Bm, rowB0, 0, 1, 1, 0);
    STG(A,  rowA0, 1, 0, 0, 1); STG(A,  rowA0, 1, 1, 0, 1);
    asm volatile("s_waitcnt vmcnt(2)" ::: "memory");
    BAR();

    for (int kt = 0; kt < NT32; ++kt) {
        const int cur = kt & 1;
        const int nc  = cur ^ 1;
        const short* Ab = lds + cur * 16384;
        const short* Bb = Ab + 8192;
        bf16x8 a[8], b0, b1, b2, b3;

        // ---- P1
        #pragma unroll
        for (int fm = 0; fm < 8; ++fm) a[fm] = *reinterpret_cast<const bf16x8*>(Ab + aRd + fm * 512);
        b0 = *reinterpret_cast<const bf16x8*>(Bb + bRd);
        b1 = *reinterpret_cast<const bf16x8*>(Bb + bRd + 512);
        if (kt + 1 < NT32) {
            STG(Bm, rowB0, kt + 1, 0, 1, nc); STG(Bm, rowB0, kt + 1, 1, 1, nc);
        }
        BAR();
        __builtin_amdgcn_s_setprio(1);
        #pragma unroll
        for (int fm = 0; fm < 8; ++fm) {
            acc[fm][0] = MFMA16(b0, a[fm], acc[fm][0]);
            acc[fm][1] = MFMA16(b1, a[fm], acc[fm][1]);
        }
        __builtin_amdgcn_s_setprio(0);
        BAR();

        // ---- P2
        b2 = *reinterpret_cast<const bf16x8*>(Bb + bRd + 1024);
        b3 = *reinterpret_cast<const bf16x8*>(Bb + bRd + 1536);
        if (kt + 2 < NT32) {
            STG(A, rowA0, kt + 2, 0, 0, cur); STG(A, rowA0, kt + 2, 1, 0, cur);
        }
        BAR();
        __builtin_amdgcn_s_setprio(1);
        #pragma unroll
        for (int fm = 0; fm < 8; ++fm) {
            acc[fm][2] = MFMA16(b2, a[fm], acc[fm][2]);
            acc[fm][3] = MFMA16(b3, a[fm], acc[fm][3]);
        }
        __builtin_amdgcn_s_setprio(0);
        if (kt < NT32 - 2) { asm volatile("s_waitcnt vmcnt(2)" ::: "memory"); }
        else               { asm volatile("s_waitcnt vmcnt(0)" ::: "memory"); }
        BAR();
    }

    const int rowBase = bm * 256 + wr * 128;
    const int colBase = bn * 256 + wc * 64;
    if (mode == 0) {
        const int seg = (colBase >> 10);
        const float* bs = (seg == 0) ? bb0 : ((seg == 1) ? bb1 : bb2);
#pragma unroll
        for (int fm = 0; fm < 8; ++fm) {
            int row = rowBase + fm * 16 + lr;
            unsigned short* cp = Cb + (size_t)row * 3072;
#pragma unroll
            for (int fn = 0; fn < 4; ++fn) {
                int col0 = colBase + fn * 16 + kg * 4;
                float4 b4 = *reinterpret_cast<const float4*>(bs + (col0 & 1023));
                float v0 = acc[fm][fn][0] + b4.x;
                float v1 = acc[fm][fn][1] + b4.y;
                float v2 = acc[fm][fn][2] + b4.z;
                float v3 = acc[fm][fn][3] + b4.w;
                float r0, r1, r2, r3;
                if (seg == 0)      { r0 = __expf(v0); r1 = __expf(v1); r2 = __expf(v2); r3 = __expf(v3); }
                else if (seg == 1) { r0 = sigmoidf_(v0); r1 = sigmoidf_(v1); r2 = sigmoidf_(v2); r3 = sigmoidf_(v3); }
                else               { r0 = sigmoidf_(v0 * KAPPA); r1 = sigmoidf_(v1 * KAPPA);
                                     r2 = sigmoidf_(v2 * KAPPA); r3 = sigmoidf_(v3 * KAPPA); }
                uint2 p;
                p.x = pack2(r0, r1);
                p.y = pack2(r2, r3);
                *reinterpret_cast<uint2*>(cp + col0) = p;
            }
        }
    } else {
#pragma unroll
        for (int fm = 0; fm < 8; ++fm) {
            int row = rowBase + fm * 16 + lr;
            float* cp = Cf + (size_t)row * 1024;
#pragma unroll
            for (int fn = 0; fn < 4; ++fn) {
                int col0 = colBase + fn * 16 + kg * 4;
                float4 b4 = *reinterpret_cast<const float4*>(bb0 + col0);
                float4 v;
                v.x = acc[fm][fn][0] + b4.x;
                v.y = acc[fm][fn][1] + b4.y;
                v.z = acc[fm][fn][2] + b4.z;
                v.w = acc[fm][fn][3] + b4.w;
                *reinterpret_cast<float4*>(cp + col0) = v;
            }
        }
    }
#undef STG
}

// ============================================================================
// Split scan chain, 2 channels/thread (uint = 2 bf16 per load).
// Block: blockIdx.x = (b*64 + c)*2 + dq; 256 threads; d0 = dq*512 + thr*2.
// Partials layout: [b*64+c][512 dpairs] float2, dpair = dq*256 + thr.
// ============================================================================

// pass1: per-(b,chunk) partial sums of K and K*V
__global__ __launch_bounds__(256) void pass1v(
        const unsigned short* __restrict__ KQ, const unsigned short* __restrict__ xbf,
        float2* __restrict__ pK, float2* __restrict__ pKV) {
    const int thr = threadIdx.x;
    const int dq = blockIdx.x & 1;
    const int bc = blockIdx.x >> 1;
    const int b = bc >> 6, c = bc & 63;
    const int d0 = dq * 512 + thr * 2;
    const size_t row0 = (size_t)b * L_DIM + (size_t)c * 64;
    const unsigned short* kp = KQ  + row0 * 3072 + d0;
    const unsigned short* vp = xbf + row0 * 1024 + d0;
    float sK0 = 0.f, sK1 = 0.f, sKV0 = 0.f, sKV1 = 0.f;
#pragma unroll 8
    for (int t = 0; t < 64; ++t) {
        unsigned ku = *reinterpret_cast<const unsigned*>(kp + (size_t)t * 3072);
        unsigned vu = *reinterpret_cast<const unsigned*>(vp + (size_t)t * 1024);
        sK0 += bflo(ku); sK1 += bfhi(ku);
        sKV0 += bflo(ku) * bflo(vu); sKV1 += bfhi(ku) * bfhi(vu);
    }
    const size_t slot = (size_t)bc * 512 + dq * 256 + thr;
    pK[slot]  = make_float2(sK0, sK1);
    pKV[slot] = make_float2(sKV0, sKV1);
}

// pass3: lookback over pK/pKV, then z[t] = oar[t] + P[t]*KAPPA*q[t-1]; chunk sum of m
__global__ __launch_bounds__(256) void pass3v(
        const unsigned short* __restrict__ KQ, const unsigned short* __restrict__ xbf,
        const float2* __restrict__ pK, const float2* __restrict__ pKV,
        unsigned short* __restrict__ z, float2* __restrict__ pM) {
    const int thr = threadIdx.x;
    const int dq = blockIdx.x & 1;
    const int bc = blockIdx.x >> 1;
    const int b = bc >> 6, c = bc & 63;
    const int d0 = dq * 512 + thr * 2;
    const size_t row0 = (size_t)b * L_DIM + (size_t)c * 64;
    const unsigned short* kqp = KQ  + row0 * 3072 + d0;   // k:+0  q:+1024  k2:+2048
    const unsigned short* vp  = xbf + row0 * 1024 + d0;
    unsigned short* zp = z + row0 * 1024 + d0;

    // lookback: exclusive prefix over chunks (ascending -> deterministic)
    float cK0 = 0.f, cK1 = 0.f, cKV0 = 0.f, cKV1 = 0.f;
    const size_t base = (size_t)(b << 6) * 512 + dq * 256 + thr;
#pragma unroll 4
    for (int cp = 0; cp < c; ++cp) {
        float2 a = pK [base + (size_t)cp * 512];
        float2 q2 = pKV[base + (size_t)cp * 512];
        cK0 += a.x; cK1 += a.y; cKV0 += q2.x; cKV1 += q2.y;
    }

    float oar_prev0 = 0.f, oar_prev1 = 0.f, k2_prev0 = 0.f, k2_prev1 = 0.f;
    float q_prev0 = 0.f, q_prev1 = 0.f;
    if (c != 0) {
        unsigned qm  = *reinterpret_cast<const unsigned*>(kqp - 3072 + 1024);
        unsigned k2m = *reinterpret_cast<const unsigned*>(kqp - 3072 + 2048);
        oar_prev0 = bflo(qm) * (cKV0 / (cK0 + 1e-6f));
        oar_prev1 = bfhi(qm) * (cKV1 / (cK1 + 1e-6f));
        k2_prev0 = bflo(k2m); k2_prev1 = bfhi(k2m);
        q_prev0 = bflo(qm);   q_prev1 = bfhi(qm);
    }
    float sM0 = 0.f, sM1 = 0.f;
#pragma unroll 4
    for (int t = 0; t < 64; ++t) {
        unsigned ku  = *reinterpret_cast<const unsigned*>(kqp + (size_t)t * 3072);
        unsigned qu  = *reinterpret_cast<const unsigned*>(kqp + (size_t)t * 3072 + 1024);
        unsigned k2u = *reinterpret_cast<const unsigned*>(kqp + (size_t)t * 3072 + 2048);
        unsigned vu  = *reinterpret_cast<const unsigned*>(vp  + (size_t)t * 1024);
        float v0 = bflo(vu), v1 = bfhi(vu);
        cK0 += bflo(ku); cKV0 += bflo(ku) * v0;
        cK1 += bfhi(ku); cKV1 += bfhi(ku) * v1;
        float oar0 = bflo(qu) * (cKV0 / (cK0 + 1e-6f));
        float oar1 = bfhi(qu) * (cKV1 / (cK1 + 1e-6f));
        float m0 = k2_prev0 * (v0 - oar_prev0);   // t==0 && c==0: all zero -> m=0
        float m1 = k2_prev1 * (v1 - oar_prev1);
        sM0 += m0; sM1 += m1;
        float z0 = oar0 + sM0 * KAPPA * q_prev0;
        float z1 = oar1 + sM1 * KAPPA * q_prev1;
        *reinterpret_cast<unsigned*>(zp + (size_t)t * 1024) = pack2(z0, z1);
        oar_prev0 = oar0; oar_prev1 = oar1;
        k2_prev0 = bflo(k2u); k2_prev1 = bfhi(k2u);
        q_prev0 = bflo(qu);   q_prev1 = bfhi(qu);
    }
    pM[(size_t)bc * 512 + dq * 256 + thr] = make_float2(sM0, sM1);
}

// pass5: yin[t] = z[t] + offM*KAPPA*q[t-1], in place on z. chunk 0: identity.
__global__ __launch_bounds__(256) void pass5v(
        const unsigned short* __restrict__ KQ, unsigned short* __restrict__ zy,
        const float2* __restrict__ pM) {
    const int thr = threadIdx.x;
    const int dq = blockIdx.x & 1;
    const int bc = blockIdx.x >> 1;
    const int b = bc >> 6, c = bc & 63;
    if (c == 0) return;                    // offM == 0 -> yin == z
    const int d0 = dq * 512 + thr * 2;
    const size_t row0 = (size_t)b * L_DIM + (size_t)c * 64;

    float offM0 = 0.f, offM1 = 0.f;
    const size_t base = (size_t)(b << 6) * 512 + dq * 256 + thr;
#pragma unroll 4
    for (int cp = 0; cp < c; ++cp) {
        float2 a = pM[base + (size_t)cp * 512];
        offM0 += a.x; offM1 += a.y;
    }
    const float s0 = offM0 * KAPPA, s1 = offM1 * KAPPA;
    const unsigned short* qp = KQ + (row0 - 1) * 3072 + 1024 + d0;   // q[t-1]
    unsigned short* zp = zy + row0 * 1024 + d0;
#pragma unroll 8
    for (int t = 0; t < 64; ++t) {
        unsigned qu = *reinterpret_cast<const unsigned*>(qp + (size_t)t * 3072);
        unsigned zu = *reinterpret_cast<const unsigned*>(zp + (size_t)t * 1024);
        float y0 = bflo(zu) + s0 * bflo(qu);
        float y1 = bfhi(zu) + s1 * bfhi(qu);
        *reinterpret_cast<unsigned*>(zp + (size_t)t * 1024) = pack2(y0, y1);
    }
}

extern "C" void kernel_launch(void* const* d_in, const int* in_sizes, int n_in,
                              void* d_out, int out_size, void* d_ws, size_t ws_size,
                              hipStream_t stream) {
    (void)in_sizes; (void)n_in; (void)out_size; (void)ws_size;
    const float* x   = (const float*)d_in[0];
    const float* Wq1 = (const float*)d_in[1];
    const float* bq1 = (const float*)d_in[2];
    const float* Wk1 = (const float*)d_in[3];
    const float* bk1 = (const float*)d_in[4];
    const float* Wk2 = (const float*)d_in[5];
    const float* bk2 = (const float*)d_in[6];
    const float* Wpj = (const float*)d_in[7];
    const float* bpj = (const float*)d_in[8];
    float* out = (float*)d_out;

    char* ws = (char*)d_ws;
    unsigned short* xbf   = (unsigned short*)(ws);                  // 33,554,432 B
    unsigned short* Wcat  = (unsigned short*)(ws + 33554432);       //  6,291,456 B (Wk1|Wq1|Wk2)
    unsigned short* Wpjbf = (unsigned short*)(ws + 39845888);       //  2,097,152 B (contiguous after Wcat)
    unsigned short* KQ    = (unsigned short*)(ws + 41943040);       // 100,663,296 B
    unsigned short* zy    = (unsigned short*)(ws + 142606336);      // 33,554,432 B (z, then yin in place)
    float2* pK  = (float2*)(ws + 176160768);                        // 1,048,576 B
    float2* pKV = (float2*)(ws + 177209344);                        // 1,048,576 B
    float2* pM  = (float2*)(ws + 178257920);                        // 1,048,576 B
    // total ~171 MiB

    (void)hipFuncSetAttribute((const void*)gemm256,
                              hipFuncAttributeMaxDynamicSharedMemorySize, 65536);

    // merged conversions: x + 4 weight matrices (Wcat|Wpjbf contiguous)
    cvt_all_kernel<<<20480, 256, 0, stream>>>(x, Wk1, Wq1, Wk2, Wpj, xbf, Wcat);

    // GEMM1: 16384 x 3072 x 1024, bf16 out with activations
    gemm256<<<dim3(64, 12), 512, 65536, stream>>>(xbf, Wcat, KQ, nullptr,
                                                  bk1, bq1, bk2, 96, 0);

    // scan chain: pass1 -> pass3 (z) -> pass5 (yin in place)
    pass1v<<<512, 256, 0, stream>>>(KQ, xbf, pK, pKV);
    pass3v<<<512, 256, 0, stream>>>(KQ, xbf, pK, pKV, zy, pM);
    pass5v<<<512, 256, 0, stream>>>(KQ, zy, pM);

    // GEMM2: 16384 x 1024 x 1024, fp32 out with bias
    gemm256<<<dim3(64, 4), 512, 65536, stream>>>(zy, Wpjbf, nullptr, out,
                                                 bpj, nullptr, nullptr, 32, 1);
}

// Round 12
// 262.694 us; speedup vs baseline: 5.8739x; 1.0234x over previous
//
#include <hip/hip_runtime.h>

// Problem constants
#define D_DIM 1024
#define L_DIM 4096
#define B_DIM 4
#define M_DIM (B_DIM * L_DIM)   // 16384 rows
#define N1    3072              // concat of K1|Q1|K2 outputs
#define KDIM  1024
#define NKT   16                // K tiles of 64
#define KAPPA 6.25e-4f          // 0.02 / sqrt(1024)

using f32x4  = __attribute__((ext_vector_type(4))) float;
using bf16x8 = __attribute__((ext_vector_type(8))) short;

__device__ __forceinline__ unsigned short f2bf(float f) {
    unsigned u = __float_as_uint(f);
    u += 0x7fffu + ((u >> 16) & 1u);   // RNE
    return (unsigned short)(u >> 16);
}
__device__ __forceinline__ float bflo(unsigned u) { return __uint_as_float(u << 16); }
__device__ __forceinline__ float bfhi(unsigned u) { return __uint_as_float(u & 0xffff0000u); }
__device__ __forceinline__ unsigned pack2(float a, float b) {
    return (unsigned)f2bf(a) | ((unsigned)f2bf(b) << 16);
}
__device__ __forceinline__ float sigmoidf_(float x) {
    return 1.0f / (1.0f + __expf(-x));
}

// merged fp32->bf16 conversion: x (16384 blocks) then 4 weight mats (4096 blocks)
__global__ void cvt_all_kernel(const float* __restrict__ x,
                               const float* __restrict__ w0, const float* __restrict__ w1,
                               const float* __restrict__ w2, const float* __restrict__ w3,
                               unsigned short* __restrict__ xbf, unsigned short* __restrict__ wout) {
    int bid = blockIdx.x;
    const float* src;
    unsigned short* dst;
    int i;
    if (bid < 16384) {
        src = x; dst = xbf;
        i = (bid * 256 + threadIdx.x) * 4;
    } else {
        int wb = bid - 16384;
        int seg = wb >> 10;
        src = (seg == 0) ? w0 : (seg == 1) ? w1 : (seg == 2) ? w2 : w3;
        dst = wout + seg * 1048576;
        i = ((wb & 1023) * 256 + threadIdx.x) * 4;
    }
    float4 v = *reinterpret_cast<const float4*>(src + i);
    uint2 p;
    p.x = pack2(v.x, v.y);
    p.y = pack2(v.z, v.w);
    *reinterpret_cast<uint2*>(dst + i) = p;
}

__device__ __forceinline__ void gld_lds16(const void* g, void* s) {
    __builtin_amdgcn_global_load_lds((const __attribute__((address_space(1))) void*)g,
                                     (__attribute__((address_space(3))) void*)s, 16, 0, 0);
}

#define BAR()  do { asm volatile("" ::: "memory"); __builtin_amdgcn_s_barrier(); asm volatile("" ::: "memory"); } while (0)
#define MFMA16(a_, b_, c_) __builtin_amdgcn_mfma_f32_16x16x32_bf16(a_, b_, c_, 0, 0, 0)

// ============================================================================
// 256x256 tile, BK=64, 8 waves (2M x 4N), 512 threads, 128 KiB LDS dbuf.
// Round-8 best-known schedule (758 TF GEMM1): 4 phases/K-tile, counted
// vmcnt(4) once per tile, distributed ds_reads + 2 gld_lds per phase.
// ============================================================================
__global__ __launch_bounds__(512, 2) void gemm256(
        const unsigned short* __restrict__ A, const unsigned short* __restrict__ Bm,
        unsigned short* __restrict__ Cb, float* __restrict__ Cf,
        const float* __restrict__ bb0, const float* __restrict__ bb1, const float* __restrict__ bb2,
        int nwgDiv8, int mode) {
    extern __shared__ __align__(16) short lds[];
    const int tid  = threadIdx.x;
    const int wid  = tid >> 6, lane = tid & 63;
    const int wr   = wid >> 2, wc = wid & 3;
    const int lr   = lane & 15, kg = lane >> 4;

    int lin = blockIdx.y * 64 + blockIdx.x;
    int swz = (lin & 7) * nwgDiv8 + (lin >> 3);
    int bm = swz & 63;
    int bn = swz >> 6;
    const size_t rowA0 = (size_t)bm * 256;
    const size_t rowB0 = (size_t)bn * 256;

    const int rh = tid >> 2;
    const int sl = (tid & 3) ^ ((rh >> 1) & 3);
    const int wbase = (tid >> 6) * 512;
    const size_t aoffG = (size_t)rh * KDIM + sl * 8;

#define STAGE(Mp_, row0_, kt_, kh_, c_, mat_, cur_) \
    gld_lds16((Mp_) + ((row0_) + (size_t)(c_) * 128) * KDIM + (size_t)(kt_) * 64 + (kh_) * 32 + aoffG, \
              (void*)(lds + (cur_) * 32768 + (mat_) * 16384 + (kh_) * 8192 + (c_) * 4096 + wbase))

    const int slotR = kg ^ ((lr >> 1) & 3);
    const int aRd = (wr * 128 + lr) * 32 + slotR * 8;
    const int bRd = (wc * 64  + lr) * 32 + slotR * 8;

    f32x4 acc[8][4];
#pragma unroll
    for (int i = 0; i < 8; ++i)
#pragma unroll
        for (int j = 0; j < 4; ++j) acc[i][j] = (f32x4){0.f, 0.f, 0.f, 0.f};

    STAGE(A,  rowA0, 0, 0, 0, 0, 0); STAGE(A,  rowA0, 0, 0, 1, 0, 0);
    STAGE(Bm, rowB0, 0, 0, 0, 1, 0); STAGE(Bm, rowB0, 0, 0, 1, 1, 0);
    STAGE(A,  rowA0, 0, 1, 0, 0, 0); STAGE(A,  rowA0, 0, 1, 1, 0, 0);
    STAGE(Bm, rowB0, 0, 1, 0, 1, 0); STAGE(Bm, rowB0, 0, 1, 1, 1, 0);
    STAGE(A,  rowA0, 1, 0, 0, 0, 1); STAGE(A,  rowA0, 1, 0, 1, 0, 1);
    STAGE(Bm, rowB0, 1, 0, 0, 1, 1); STAGE(Bm, rowB0, 1, 0, 1, 1, 1);
    asm volatile("s_waitcnt vmcnt(4)" ::: "memory");
    BAR();

    for (int kt = 0; kt < NKT; ++kt) {
        const int cur = kt & 1;
        const int nc  = cur ^ 1;
        const short* A0 = lds + cur * 32768;
        const short* A1 = A0 + 8192;
        const short* B0 = A0 + 16384;
        const short* B1 = A0 + 24576;
        bf16x8 a[8], b0, b1, b2, b3;

        // ---- P1: read a(kh0)x8 + b0,b1(kh0); stage A(kt+1,kh1)->nc
        #pragma unroll
        for (int fm = 0; fm < 8; ++fm) a[fm] = *reinterpret_cast<const bf16x8*>(A0 + aRd + fm * 512);
        b0 = *reinterpret_cast<const bf16x8*>(B0 + bRd);
        b1 = *reinterpret_cast<const bf16x8*>(B0 + bRd + 512);
        if (kt + 1 < NKT) {
            STAGE(A, rowA0, kt + 1, 1, 0, 0, nc); STAGE(A, rowA0, kt + 1, 1, 1, 0, nc);
        }
        BAR();
        __builtin_amdgcn_s_setprio(1);
        #pragma unroll
        for (int fm = 0; fm < 8; ++fm) {
            acc[fm][0] = MFMA16(b0, a[fm], acc[fm][0]);
            acc[fm][1] = MFMA16(b1, a[fm], acc[fm][1]);
        }
        __builtin_amdgcn_s_setprio(0);
        BAR();

        // ---- P2: read b2,b3(kh0); stage B(kt+1,kh1)->nc
        b2 = *reinterpret_cast<const bf16x8*>(B0 + bRd + 1024);
        b3 = *reinterpret_cast<const bf16x8*>(B0 + bRd + 1536);
        if (kt + 1 < NKT) {
            STAGE(Bm, rowB0, kt + 1, 1, 0, 1, nc); STAGE(Bm, rowB0, kt + 1, 1, 1, 1, nc);
        }
        BAR();
        __builtin_amdgcn_s_setprio(1);
        #pragma unroll
        for (int fm = 0; fm < 8; ++fm) {
            acc[fm][2] = MFMA16(b2, a[fm], acc[fm][2]);
            acc[fm][3] = MFMA16(b3, a[fm], acc[fm][3]);
        }
        __builtin_amdgcn_s_setprio(0);
        BAR();

        // ---- P3: read a(kh1)x8 + b0,b1(kh1); stage A(kt+2,kh0)->cur
        #pragma unroll
        for (int fm = 0; fm < 8; ++fm) a[fm] = *reinterpret_cast<const bf16x8*>(A1 + aRd + fm * 512);
        b0 = *reinterpret_cast<const bf16x8*>(B1 + bRd);
        b1 = *reinterpret_cast<const bf16x8*>(B1 + bRd + 512);
        if (kt + 2 < NKT) {
            STAGE(A, rowA0, kt + 2, 0, 0, 0, cur); STAGE(A, rowA0, kt + 2, 0, 1, 0, cur);
        }
        BAR();
        __builtin_amdgcn_s_setprio(1);
        #pragma unroll
        for (int fm = 0; fm < 8; ++fm) {
            acc[fm][0] = MFMA16(b0, a[fm], acc[fm][0]);
            acc[fm][1] = MFMA16(b1, a[fm], acc[fm][1]);
        }
        __builtin_amdgcn_s_setprio(0);
        BAR();

        // ---- P4: read b2,b3(kh1); stage B(kt+2,kh0)->cur; counted vmcnt
        b2 = *reinterpret_cast<const bf16x8*>(B1 + bRd + 1024);
        b3 = *reinterpret_cast<const bf16x8*>(B1 + bRd + 1536);
        if (kt + 2 < NKT) {
            STAGE(Bm, rowB0, kt + 2, 0, 0, 1, cur); STAGE(Bm, rowB0, kt + 2, 0, 1, 1, cur);
        }
        BAR();
        __builtin_amdgcn_s_setprio(1);
        #pragma unroll
        for (int fm = 0; fm < 8; ++fm) {
            acc[fm][2] = MFMA16(b2, a[fm], acc[fm][2]);
            acc[fm][3] = MFMA16(b3, a[fm], acc[fm][3]);
        }
        __builtin_amdgcn_s_setprio(0);
        if (kt < NKT - 2) { asm volatile("s_waitcnt vmcnt(4)" ::: "memory"); }
        else              { asm volatile("s_waitcnt vmcnt(0)" ::: "memory"); }
        BAR();
    }

    const int rowBase = bm * 256 + wr * 128;
    const int colBase = bn * 256 + wc * 64;
    if (mode == 0) {
        const int seg = (colBase >> 10);
        const float* bs = (seg == 0) ? bb0 : ((seg == 1) ? bb1 : bb2);
#pragma unroll
        for (int fm = 0; fm < 8; ++fm) {
            int row = rowBase + fm * 16 + lr;
            unsigned short* cp = Cb + (size_t)row * 3072;
#pragma unroll
            for (int fn = 0; fn < 4; ++fn) {
                int col0 = colBase + fn * 16 + kg * 4;
                float4 b4 = *reinterpret_cast<const float4*>(bs + (col0 & 1023));
                float v0 = acc[fm][fn][0] + b4.x;
                float v1 = acc[fm][fn][1] + b4.y;
                float v2 = acc[fm][fn][2] + b4.z;
                float v3 = acc[fm][fn][3] + b4.w;
                float r0, r1, r2, r3;
                if (seg == 0)      { r0 = __expf(v0); r1 = __expf(v1); r2 = __expf(v2); r3 = __expf(v3); }
                else if (seg == 1) { r0 = sigmoidf_(v0); r1 = sigmoidf_(v1); r2 = sigmoidf_(v2); r3 = sigmoidf_(v3); }
                else               { r0 = sigmoidf_(v0 * KAPPA); r1 = sigmoidf_(v1 * KAPPA);
                                     r2 = sigmoidf_(v2 * KAPPA); r3 = sigmoidf_(v3 * KAPPA); }
                uint2 p;
                p.x = pack2(r0, r1);
                p.y = pack2(r2, r3);
                *reinterpret_cast<uint2*>(cp + col0) = p;
            }
        }
    } else {
#pragma unroll
        for (int fm = 0; fm < 8; ++fm) {
            int row = rowBase + fm * 16 + lr;
            float* cp = Cf + (size_t)row * 1024;
#pragma unroll
            for (int fn = 0; fn < 4; ++fn) {
                int col0 = colBase + fn * 16 + kg * 4;
                float4 b4 = *reinterpret_cast<const float4*>(bb0 + col0);
                float4 v;
                v.x = acc[fm][fn][0] + b4.x;
                v.y = acc[fm][fn][1] + b4.y;
                v.z = acc[fm][fn][2] + b4.z;
                v.w = acc[fm][fn][3] + b4.w;
                *reinterpret_cast<float4*>(cp + col0) = v;
            }
        }
    }
#undef STAGE
}

// ============================================================================
// Split scan chain, 2 channels/thread (uint = 2 bf16 per load).
// Block: blockIdx.x = (b*64 + c)*2 + dq; 256 threads; d0 = dq*512 + thr*2.
// Partials layout: [b*64+c][512 dpairs] float2, dpair = dq*256 + thr.
// ============================================================================

// pass1: per-(b,chunk) partial sums of K and K*V
__global__ __launch_bounds__(256) void pass1v(
        const unsigned short* __restrict__ KQ, const unsigned short* __restrict__ xbf,
        float2* __restrict__ pK, float2* __restrict__ pKV) {
    const int thr = threadIdx.x;
    const int dq = blockIdx.x & 1;
    const int bc = blockIdx.x >> 1;
    const int b = bc >> 6, c = bc & 63;
    const int d0 = dq * 512 + thr * 2;
    const size_t row0 = (size_t)b * L_DIM + (size_t)c * 64;
    const unsigned short* kp = KQ  + row0 * 3072 + d0;
    const unsigned short* vp = xbf + row0 * 1024 + d0;
    float sK0 = 0.f, sK1 = 0.f, sKV0 = 0.f, sKV1 = 0.f;
#pragma unroll 8
    for (int t = 0; t < 64; ++t) {
        unsigned ku = *reinterpret_cast<const unsigned*>(kp + (size_t)t * 3072);
        unsigned vu = *reinterpret_cast<const unsigned*>(vp + (size_t)t * 1024);
        sK0 += bflo(ku); sK1 += bfhi(ku);
        sKV0 += bflo(ku) * bflo(vu); sKV1 += bfhi(ku) * bfhi(vu);
    }
    const size_t slot = (size_t)bc * 512 + dq * 256 + thr;
    pK[slot]  = make_float2(sK0, sK1);
    pKV[slot] = make_float2(sKV0, sKV1);
}

// pass3: lookback over pK/pKV, then z[t] = oar[t] + P[t]*KAPPA*q[t-1]; chunk sum of m
__global__ __launch_bounds__(256) void pass3v(
        const unsigned short* __restrict__ KQ, const unsigned short* __restrict__ xbf,
        const float2* __restrict__ pK, const float2* __restrict__ pKV,
        unsigned short* __restrict__ z, float2* __restrict__ pM) {
    const int thr = threadIdx.x;
    const int dq = blockIdx.x & 1;
    const int bc = blockIdx.x >> 1;
    const int b = bc >> 6, c = bc & 63;
    const int d0 = dq * 512 + thr * 2;
    const size_t row0 = (size_t)b * L_DIM + (size_t)c * 64;
    const unsigned short* kqp = KQ  + row0 * 3072 + d0;   // k:+0  q:+1024  k2:+2048
    const unsigned short* vp  = xbf + row0 * 1024 + d0;
    unsigned short* zp = z + row0 * 1024 + d0;

    // lookback: exclusive prefix over chunks (ascending -> deterministic)
    float cK0 = 0.f, cK1 = 0.f, cKV0 = 0.f, cKV1 = 0.f;
    const size_t base = (size_t)(b << 6) * 512 + dq * 256 + thr;
#pragma unroll 4
    for (int cp = 0; cp < c; ++cp) {
        float2 a = pK [base + (size_t)cp * 512];
        float2 q2 = pKV[base + (size_t)cp * 512];
        cK0 += a.x; cK1 += a.y; cKV0 += q2.x; cKV1 += q2.y;
    }

    float oar_prev0 = 0.f, oar_prev1 = 0.f, k2_prev0 = 0.f, k2_prev1 = 0.f;
    float q_prev0 = 0.f, q_prev1 = 0.f;
    if (c != 0) {
        unsigned qm  = *reinterpret_cast<const unsigned*>(kqp - 3072 + 1024);
        unsigned k2m = *reinterpret_cast<const unsigned*>(kqp - 3072 + 2048);
        oar_prev0 = bflo(qm) * (cKV0 / (cK0 + 1e-6f));
        oar_prev1 = bfhi(qm) * (cKV1 / (cK1 + 1e-6f));
        k2_prev0 = bflo(k2m); k2_prev1 = bfhi(k2m);
        q_prev0 = bflo(qm);   q_prev1 = bfhi(qm);
    }
    float sM0 = 0.f, sM1 = 0.f;
#pragma unroll 4
    for (int t = 0; t < 64; ++t) {
        unsigned ku  = *reinterpret_cast<const unsigned*>(kqp + (size_t)t * 3072);
        unsigned qu  = *reinterpret_cast<const unsigned*>(kqp + (size_t)t * 3072 + 1024);
        unsigned k2u = *reinterpret_cast<const unsigned*>(kqp + (size_t)t * 3072 + 2048);
        unsigned vu  = *reinterpret_cast<const unsigned*>(vp  + (size_t)t * 1024);
        float v0 = bflo(vu), v1 = bfhi(vu);
        cK0 += bflo(ku); cKV0 += bflo(ku) * v0;
        cK1 += bfhi(ku); cKV1 += bfhi(ku) * v1;
        float oar0 = bflo(qu) * (cKV0 / (cK0 + 1e-6f));
        float oar1 = bfhi(qu) * (cKV1 / (cK1 + 1e-6f));
        float m0 = k2_prev0 * (v0 - oar_prev0);   // t==0 && c==0: all zero -> m=0
        float m1 = k2_prev1 * (v1 - oar_prev1);
        sM0 += m0; sM1 += m1;
        float z0 = oar0 + sM0 * KAPPA * q_prev0;
        float z1 = oar1 + sM1 * KAPPA * q_prev1;
        *reinterpret_cast<unsigned*>(zp + (size_t)t * 1024) = pack2(z0, z1);
        oar_prev0 = oar0; oar_prev1 = oar1;
        k2_prev0 = bflo(k2u); k2_prev1 = bfhi(k2u);
        q_prev0 = bflo(qu);   q_prev1 = bfhi(qu);
    }
    pM[(size_t)bc * 512 + dq * 256 + thr] = make_float2(sM0, sM1);
}

// pass5: yin[t] = z[t] + offM*KAPPA*q[t-1], in place on z. chunk 0: identity.
__global__ __launch_bounds__(256) void pass5v(
        const unsigned short* __restrict__ KQ, unsigned short* __restrict__ zy,
        const float2* __restrict__ pM) {
    const int thr = threadIdx.x;
    const int dq = blockIdx.x & 1;
    const int bc = blockIdx.x >> 1;
    const int b = bc >> 6, c = bc & 63;
    if (c == 0) return;                    // offM == 0 -> yin == z
    const int d0 = dq * 512 + thr * 2;
    const size_t row0 = (size_t)b * L_DIM + (size_t)c * 64;

    float offM0 = 0.f, offM1 = 0.f;
    const size_t base = (size_t)(b << 6) * 512 + dq * 256 + thr;
#pragma unroll 4
    for (int cp = 0; cp < c; ++cp) {
        float2 a = pM[base + (size_t)cp * 512];
        offM0 += a.x; offM1 += a.y;
    }
    const float s0 = offM0 * KAPPA, s1 = offM1 * KAPPA;
    const unsigned short* qp = KQ + (row0 - 1) * 3072 + 1024 + d0;   // q[t-1]
    unsigned short* zp = zy + row0 * 1024 + d0;
#pragma unroll 8
    for (int t = 0; t < 64; ++t) {
        unsigned qu = *reinterpret_cast<const unsigned*>(qp + (size_t)t * 3072);
        unsigned zu = *reinterpret_cast<const unsigned*>(zp + (size_t)t * 1024);
        float y0 = bflo(zu) + s0 * bflo(qu);
        float y1 = bfhi(zu) + s1 * bfhi(qu);
        *reinterpret_cast<unsigned*>(zp + (size_t)t * 1024) = pack2(y0, y1);
    }
}

extern "C" void kernel_launch(void* const* d_in, const int* in_sizes, int n_in,
                              void* d_out, int out_size, void* d_ws, size_t ws_size,
                              hipStream_t stream) {
    (void)in_sizes; (void)n_in; (void)out_size; (void)ws_size;
    const float* x   = (const float*)d_in[0];
    const float* Wq1 = (const float*)d_in[1];
    const float* bq1 = (const float*)d_in[2];
    const float* Wk1 = (const float*)d_in[3];
    const float* bk1 = (const float*)d_in[4];
    const float* Wk2 = (const float*)d_in[5];
    const float* bk2 = (const float*)d_in[6];
    const float* Wpj = (const float*)d_in[7];
    const float* bpj = (const float*)d_in[8];
    float* out = (float*)d_out;

    char* ws = (char*)d_ws;
    unsigned short* xbf   = (unsigned short*)(ws);                  // 33,554,432 B
    unsigned short* Wcat  = (unsigned short*)(ws + 33554432);       //  6,291,456 B (Wk1|Wq1|Wk2)
    unsigned short* Wpjbf = (unsigned short*)(ws + 39845888);       //  2,097,152 B (contiguous after Wcat)
    unsigned short* KQ    = (unsigned short*)(ws + 41943040);       // 100,663,296 B
    unsigned short* zy    = (unsigned short*)(ws + 142606336);      // 33,554,432 B (z, then yin in place)
    float2* pK  = (float2*)(ws + 176160768);                        // 1,048,576 B
    float2* pKV = (float2*)(ws + 177209344);                        // 1,048,576 B
    float2* pM  = (float2*)(ws + 178257920);                        // 1,048,576 B
    // total ~171 MiB

    (void)hipFuncSetAttribute((const void*)gemm256,
                              hipFuncAttributeMaxDynamicSharedMemorySize, 131072);

    // merged conversions: x + 4 weight matrices (Wcat|Wpjbf contiguous)
    cvt_all_kernel<<<20480, 256, 0, stream>>>(x, Wk1, Wq1, Wk2, Wpj, xbf, Wcat);

    // GEMM1: 16384 x 3072 x 1024, bf16 out with activations
    gemm256<<<dim3(64, 12), 512, 131072, stream>>>(xbf, Wcat, KQ, nullptr,
                                                   bk1, bq1, bk2, 96, 0);

    // scan chain: pass1 -> pass3 (z) -> pass5 (yin in place)
    pass1v<<<512, 256, 0, stream>>>(KQ, xbf, pK, pKV);
    pass3v<<<512, 256, 0, stream>>>(KQ, xbf, pK, pKV, zy, pM);
    pass5v<<<512, 256, 0, stream>>>(KQ, zy, pM);

    // GEMM2: 16384 x 1024 x 1024, fp32 out with bias
    gemm256<<<dim3(64, 4), 512, 131072, stream>>>(zy, Wpjbf, nullptr, out,
                                                  bpj, nullptr, nullptr, 32, 1);
}